// Round 3
// baseline (4450.223 us; speedup 1.0000x reference)
//
#include <hip/hip_runtime.h>
#include <hip/hip_cooperative_groups.h>
#include <math.h>

namespace cg = cooperative_groups;

// Sinkhorn via potentials, single persistent cooperative kernel.
//
// Identity: after any number of alternating row/col log-normalizations,
// log_m = m + u[i] + v[j] on valid entries. Work in base-2 linear domain:
//   p[b,i,j]  = 2^(m*log2e), 0 for j>=ncols (masking is free)
//   row pass:  s_i = sum_j p*wv_j  -> u_i = -log2(s), wu_i = 1/s (=2^u)
//   col pass:  s_j = sum_i p*wu_i  -> v_j = -log2(s), wv_j = 1/s
//   final:     out = exp2(m*log2e + u + v) on valid, else 0   (fp32 m)
// Inner loops are pure fma dot products - no transcendentals.
//
// p (fp16, 128MB) lives in d_out (scratch until final overwrites; final
// reads fp32 m, not p, so overwrite is safe).
// d_ws: u,wu [B*N], v,wv [B*M], ps partials [B*4*16*256], counters.

typedef _Float16 h16;
typedef _Float16 h8_t __attribute__((ext_vector_type(8)));

#define LOG2E 1.4426950408889634f
#define NCU 256  // MI355X CUs

constexpr int N = 1024, M = 1024;

__device__ __forceinline__ float wave_sum64(float v) {
#pragma unroll
    for (int o = 32; o > 0; o >>= 1) v += __shfl_xor(v, o, 64);
    return v;
}

__global__ __launch_bounds__(256, 4) void sinkhorn_coop(
    const float* __restrict__ m, const int* __restrict__ nrows,
    const int* __restrict__ ncols, float* __restrict__ out,
    h16* __restrict__ p, float* __restrict__ wsf, int B) {
    const int tid = blockIdx.x * blockDim.x + threadIdx.x;
    const int lane = threadIdx.x & 63;
    const int w = tid >> 6;
    const int nw = (gridDim.x * blockDim.x) >> 6;
    const int nthreads = gridDim.x * blockDim.x;

    float* u = wsf;
    float* wu = u + (size_t)B * N;
    float* v = wu + (size_t)B * N;
    float* wv = v + (size_t)B * M;
    float* ps = wv + (size_t)B * M;              // B*4*16*256 floats
    int* cnt = (int*)(ps + (size_t)B * 16384);
    int* cnt_row = cnt;                          // [10][64]
    int* cnt_fin = cnt + 640;                    // [64]
    int* done = cnt + 704;                       // [10][B*4]

    cg::grid_group grid = cg::this_grid();

    // ---- init counters ----
    const int n_ints = 704 + 10 * B * 4;
    for (int i = tid; i < n_ints; i += nthreads) cnt[i] = 0;
    grid.sync();

    // ---- R0: fp32 read, build masked p, u = -log2(sum p) ----
    {
        const int pool = w & 63;
        int* c = &cnt_row[pool];
        const int ntask = B * (N / 64);
        for (;;) {
            int j0;
            if (lane == 0) j0 = atomicAdd(c, 2);
            j0 = __shfl(j0, 0);
            if (j0 >= ntask) break;
            const int jend = min(j0 + 2, ntask);
            for (int j = j0; j < jend; ++j) {
                const int b = j >> 4;
                const int row = ((j & 15) << 6) + pool;
                if (row >= nrows[b]) continue;
                const int nc = ncols[b];
                const float* rp = m + ((size_t)b * N + row) * M;
                h16* pp = p + ((size_t)b * N + row) * M;
                float s = 0.f;
#pragma unroll
                for (int k = 0; k < 2; ++k) {
                    const int j8 = lane * 8 + (k << 9);
                    const float4 a0 = *(const float4*)(rp + j8);
                    const float4 a1 = *(const float4*)(rp + j8 + 4);
                    float pe[8];
                    pe[0] = __builtin_amdgcn_exp2f(a0.x * LOG2E);
                    pe[1] = __builtin_amdgcn_exp2f(a0.y * LOG2E);
                    pe[2] = __builtin_amdgcn_exp2f(a0.z * LOG2E);
                    pe[3] = __builtin_amdgcn_exp2f(a0.w * LOG2E);
                    pe[4] = __builtin_amdgcn_exp2f(a1.x * LOG2E);
                    pe[5] = __builtin_amdgcn_exp2f(a1.y * LOG2E);
                    pe[6] = __builtin_amdgcn_exp2f(a1.z * LOG2E);
                    pe[7] = __builtin_amdgcn_exp2f(a1.w * LOG2E);
                    h8_t hv;
#pragma unroll
                    for (int e = 0; e < 8; ++e) {
                        pe[e] = (j8 + e < nc) ? pe[e] : 0.f;  // mask cols
                        hv[e] = (h16)pe[e];
                        s += pe[e];
                    }
                    *(h8_t*)(pp + j8) = hv;
                }
                s = wave_sum64(s);
                if (lane == 0) {
                    const bool ok = s > 0.f;
                    u[(size_t)b * N + row] = ok ? -__builtin_amdgcn_logf(s) : 0.f;
                    wu[(size_t)b * N + row] = ok ? __builtin_amdgcn_rcpf(s) : 0.f;
                }
            }
        }
    }
    grid.sync();

    for (int t = 0; t < 10; ++t) {
        // ---- Col pass: partial sums over 64-row chunks + inline combine ----
        {
            const int ntask = B * 64;  // (b, cc<4, rc<16)
            for (int task = w; task < ntask; task += nw) {
                const int b = task >> 6;
                const int rc = task & 15;
                const int r0 = rc << 6;
                const int nr = nrows[b];
                float4 acc = make_float4(0.f, 0.f, 0.f, 0.f);
                if (r0 < nr) {
                    const int cc = (task >> 4) & 3;
                    const int rows = min(64, nr - r0);
                    const float uwv = wu[(size_t)b * N + r0 + lane];
                    const h16* pb = p + ((size_t)b * N + r0) * M + cc * 256 + lane * 4;
                    int i = 0;
                    for (; i + 4 <= rows; i += 4) {  // 4-deep MLP
                        const h8_t* q0 = (const h8_t*)(pb + (size_t)i * M);
                        const h16* a0 = pb + (size_t)(i + 0) * M;
                        const h16* a1 = pb + (size_t)(i + 1) * M;
                        const h16* a2 = pb + (size_t)(i + 2) * M;
                        const h16* a3 = pb + (size_t)(i + 3) * M;
                        (void)q0;
                        const float w0 = __shfl(uwv, i + 0);
                        const float w1 = __shfl(uwv, i + 1);
                        const float w2 = __shfl(uwv, i + 2);
                        const float w3 = __shfl(uwv, i + 3);
                        acc.x += (float)a0[0] * w0 + (float)a1[0] * w1 + (float)a2[0] * w2 + (float)a3[0] * w3;
                        acc.y += (float)a0[1] * w0 + (float)a1[1] * w1 + (float)a2[1] * w2 + (float)a3[1] * w3;
                        acc.z += (float)a0[2] * w0 + (float)a1[2] * w1 + (float)a2[2] * w2 + (float)a3[2] * w3;
                        acc.w += (float)a0[3] * w0 + (float)a1[3] * w1 + (float)a2[3] * w3 * 0.f + (float)a3[3] * w3;
                        // note: fix typo below (recomputed cleanly)
                        acc.w += (float)a2[3] * w2;
                    }
                    for (; i < rows; ++i) {
                        const h16* a0 = pb + (size_t)i * M;
                        const float w0 = __shfl(uwv, i);
                        acc.x += (float)a0[0] * w0;
                        acc.y += (float)a0[1] * w0;
                        acc.z += (float)a0[2] * w0;
                        acc.w += (float)a0[3] * w0;
                    }
                }
                *(float4*)(ps + (size_t)task * 256 + lane * 4) = acc;
                __threadfence();
                int old;
                if (lane == 0) old = atomicAdd(&done[t * (B * 4) + (task >> 4)], 1);
                old = __shfl(old, 0);
                if (old == 15) {  // last finisher combines the 16 partials
                    __threadfence();
                    const int grp = task >> 4;       // b*4 + cc
                    const int b2 = grp >> 2;
                    const int cc2 = grp & 3;
                    const float* pbase = ps + (size_t)grp * 16 * 256 + lane * 4;
                    float4 cs = make_float4(0.f, 0.f, 0.f, 0.f);
#pragma unroll
                    for (int r = 0; r < 16; ++r) {
                        const float4 q = *(const float4*)(pbase + r * 256);
                        cs.x += q.x; cs.y += q.y; cs.z += q.z; cs.w += q.w;
                    }
                    const size_t vo = (size_t)b2 * M + cc2 * 256 + lane * 4;
                    float4 vr, wr;
                    vr.x = cs.x > 0.f ? -__builtin_amdgcn_logf(cs.x) : 0.f;
                    vr.y = cs.y > 0.f ? -__builtin_amdgcn_logf(cs.y) : 0.f;
                    vr.z = cs.z > 0.f ? -__builtin_amdgcn_logf(cs.z) : 0.f;
                    vr.w = cs.w > 0.f ? -__builtin_amdgcn_logf(cs.w) : 0.f;
                    wr.x = cs.x > 0.f ? __builtin_amdgcn_rcpf(cs.x) : 0.f;
                    wr.y = cs.y > 0.f ? __builtin_amdgcn_rcpf(cs.y) : 0.f;
                    wr.z = cs.z > 0.f ? __builtin_amdgcn_rcpf(cs.z) : 0.f;
                    wr.w = cs.w > 0.f ? __builtin_amdgcn_rcpf(cs.w) : 0.f;
                    *(float4*)(v + vo) = vr;
                    *(float4*)(wv + vo) = wr;
                }
            }
        }
        grid.sync();
        if (t == 9) break;

        // ---- Row pass: s = sum_j p*wv, u = -log2 s ----
        {
            const int pool = w & 63;
            int* c = &cnt_row[(t + 1) * 64 + pool];
            const int ntask = B * (N / 64);
            for (;;) {
                int j0;
                if (lane == 0) j0 = atomicAdd(c, 2);
                j0 = __shfl(j0, 0);
                if (j0 >= ntask) break;
                const int jend = min(j0 + 2, ntask);
                for (int j = j0; j < jend; ++j) {
                    const int b = j >> 4;
                    const int row = ((j & 15) << 6) + pool;
                    if (row >= nrows[b]) continue;
                    const h16* pp = p + ((size_t)b * N + row) * M;
                    const float* wvb = wv + (size_t)b * M;
                    float s = 0.f;
#pragma unroll
                    for (int k = 0; k < 2; ++k) {
                        const int j8 = lane * 8 + (k << 9);
                        const h8_t a = *(const h8_t*)(pp + j8);
                        const float4 w0 = *(const float4*)(wvb + j8);
                        const float4 w1 = *(const float4*)(wvb + j8 + 4);
                        s += (float)a[0] * w0.x + (float)a[1] * w0.y +
                             (float)a[2] * w0.z + (float)a[3] * w0.w +
                             (float)a[4] * w1.x + (float)a[5] * w1.y +
                             (float)a[6] * w1.z + (float)a[7] * w1.w;
                    }
                    s = wave_sum64(s);
                    if (lane == 0) {
                        const bool ok = s > 0.f;
                        u[(size_t)b * N + row] = ok ? -__builtin_amdgcn_logf(s) : 0.f;
                        wu[(size_t)b * N + row] = ok ? __builtin_amdgcn_rcpf(s) : 0.f;
                    }
                }
            }
        }
        grid.sync();
    }

    // ---- Final: out = exp2(m*log2e + u + v) masked; fp32 m for accuracy ----
    {
        const int pool = w & 63;
        int* c = &cnt_fin[pool];
        const int ntask = B * (N / 64);
        for (;;) {
            int j0;
            if (lane == 0) j0 = atomicAdd(c, 2);
            j0 = __shfl(j0, 0);
            if (j0 >= ntask) break;
            const int jend = min(j0 + 2, ntask);
            for (int j = j0; j < jend; ++j) {
                const int b = j >> 4;
                const int row = ((j & 15) << 6) + pool;
                float* op = out + ((size_t)b * N + row) * M;
                if (row >= nrows[b]) {
                    const float4 z = make_float4(0.f, 0.f, 0.f, 0.f);
#pragma unroll
                    for (int k = 0; k < 2; ++k) {
                        const int j8 = lane * 8 + (k << 9);
                        *(float4*)(op + j8) = z;
                        *(float4*)(op + j8 + 4) = z;
                    }
                    continue;
                }
                const int nc = ncols[b];
                const float ui = u[(size_t)b * N + row];
                const float* rp = m + ((size_t)b * N + row) * M;
                const float* vb = v + (size_t)b * M;
#pragma unroll
                for (int k = 0; k < 2; ++k) {
                    const int j8 = lane * 8 + (k << 9);
                    const float4 a0 = *(const float4*)(rp + j8);
                    const float4 a1 = *(const float4*)(rp + j8 + 4);
                    const float4 v0 = *(const float4*)(vb + j8);
                    const float4 v1 = *(const float4*)(vb + j8 + 4);
                    float4 r0, r1;
                    r0.x = (j8 + 0 < nc) ? __builtin_amdgcn_exp2f(fmaf(a0.x, LOG2E, ui + v0.x)) : 0.f;
                    r0.y = (j8 + 1 < nc) ? __builtin_amdgcn_exp2f(fmaf(a0.y, LOG2E, ui + v0.y)) : 0.f;
                    r0.z = (j8 + 2 < nc) ? __builtin_amdgcn_exp2f(fmaf(a0.z, LOG2E, ui + v0.z)) : 0.f;
                    r0.w = (j8 + 3 < nc) ? __builtin_amdgcn_exp2f(fmaf(a0.w, LOG2E, ui + v0.w)) : 0.f;
                    r1.x = (j8 + 4 < nc) ? __builtin_amdgcn_exp2f(fmaf(a1.x, LOG2E, ui + v1.x)) : 0.f;
                    r1.y = (j8 + 5 < nc) ? __builtin_amdgcn_exp2f(fmaf(a1.y, LOG2E, ui + v1.y)) : 0.f;
                    r1.z = (j8 + 6 < nc) ? __builtin_amdgcn_exp2f(fmaf(a1.z, LOG2E, ui + v1.z)) : 0.f;
                    r1.w = (j8 + 7 < nc) ? __builtin_amdgcn_exp2f(fmaf(a1.w, LOG2E, ui + v1.w)) : 0.f;
                    *(float4*)(op + j8) = r0;
                    *(float4*)(op + j8 + 4) = r1;
                }
            }
        }
    }
}

extern "C" void kernel_launch(void* const* d_in, const int* in_sizes, int n_in,
                              void* d_out, int out_size, void* d_ws, size_t ws_size,
                              hipStream_t stream) {
    const float* m = (const float*)d_in[0];
    const int* nrows = (const int*)d_in[1];
    const int* ncols = (const int*)d_in[2];
    int B = in_sizes[1];

    float* out = (float*)d_out;
    h16* p = (h16*)d_out;  // fp16 prob copy in d_out; safe: final reads fp32 m
    float* wsf = (float*)d_ws;

    int nb = 0;
    hipOccupancyMaxActiveBlocksPerMultiprocessor(&nb, (const void*)sinkhorn_coop, 256, 0);
    if (nb < 1) nb = 1;
    if (nb > 4) nb = 4;
    const dim3 grid(NCU * nb), block(256);

    void* args[] = {(void*)&m, (void*)&nrows, (void*)&ncols,
                    (void*)&out, (void*)&p, (void*)&wsf, (void*)&B};
    hipLaunchCooperativeKernel((const void*)sinkhorn_coop, grid, block, args, 0, stream);
}